// Round 12
// baseline (864.613 us; speedup 1.0000x reference)
//
#include <hip/hip_runtime.h>
#include <math.h>

#define NN 4096
#define CC 256
#define HH 64
#define BT 16
#define KCC 100
#define NHH 8
#define HDD 32
#define C4 1024

typedef unsigned short bf16_t;
typedef short s16x8 __attribute__((ext_vector_type(8)));
typedef float f32x4 __attribute__((ext_vector_type(4)));
typedef float f32x16 __attribute__((ext_vector_type(16)));

__device__ __forceinline__ float bf2f(bf16_t h) {
  return __uint_as_float(((unsigned)h) << 16);
}
__device__ __forceinline__ bf16_t f2bf(float f) {
  unsigned u = __float_as_uint(f);
  return (bf16_t)((u + 0x7FFFu + ((u >> 16) & 1u)) >> 16);
}

__device__ __forceinline__ float gelu_f(float x) {
  return 0.5f * x * (1.0f + erff(x * 0.7071067811865475f));
}

// async global->LDS, 16 B per lane; lds dest = wave-uniform base + lane*16
__device__ __forceinline__ void g2l16(const void* g, void* l) {
  __builtin_amdgcn_global_load_lds((const __attribute__((address_space(1))) void*)g,
                                   (__attribute__((address_space(3))) void*)l, 16, 0, 0);
}

__device__ __forceinline__ float block_sum256(float v) {
  __shared__ float sh[4];
#pragma unroll
  for (int off = 32; off; off >>= 1) v += __shfl_xor(v, off, 64);
  __syncthreads();
  if ((threadIdx.x & 63) == 0) sh[threadIdx.x >> 6] = v;
  __syncthreads();
  return sh[0] + sh[1] + sh[2] + sh[3];
}

__device__ __forceinline__ const float* xt_base(const float* x, const float* mem, int bt) {
  int b = bt >> 2, tt = bt & 3;
  return (tt < 3) ? (mem + (size_t)(b * 3 + tt) * NN * CC)
                  : (x + (size_t)b * NN * CC);
}

// fused prologue: [0,16384) build xtb; [16384,19520) transpose conv1_w -> wtb;
// [19520,22436) convert 6 weight mats to bf16 pack wbz.
__global__ __launch_bounds__(256) void prologue(const float* __restrict__ x,
                                                const float* __restrict__ mem,
                                                bf16_t* __restrict__ xtb,
                                                const float* __restrict__ w1,
                                                bf16_t* __restrict__ wtb,
                                                const float* __restrict__ c2w,
                                                const float* __restrict__ c3w,
                                                const float* __restrict__ qw,
                                                const float* __restrict__ pw,
                                                const float* __restrict__ f1w,
                                                const float* __restrict__ f2w,
                                                bf16_t* __restrict__ wbz) {
  int bid = blockIdx.x;
  int tid = threadIdx.x;
  if (bid < 16384) {
    int i = bid * 256 + tid;
    int c4 = i & 63;
    int n = (i >> 6) & 4095;
    int bt = i >> 18;
    const float* src = xt_base(x, mem, bt) + (size_t)n * CC + c4 * 4;
    float4 v = *(const float4*)src;
    ushort4 o;
    o.x = f2bf(v.x); o.y = f2bf(v.y); o.z = f2bf(v.z); o.w = f2bf(v.w);
    *(ushort4*)(xtb + (size_t)i * 4) = o;
  } else if (bid < 19520) {
    int i = (bid - 16384) * 256 + tid;  // < 802816 exactly
    int cj = i & 7;
    int t = i >> 3;
    int co = t & 63; t >>= 6;
    int oc = t & 3; t >>= 2;
    int kx = t % 7; t /= 7;
    int cq = t & 3; t >>= 2;
    int cg = t & 7;
    int ky = t >> 3;
    int ci = cg * 32 + oc * 8 + cj;
    int cog = cq * 64 + co;
    wtb[i] = f2bf(w1[((size_t)(cog * CC + ci) * 7 + ky) * 7 + kx]);
  } else {
    int j = (bid - 19520) * 256 + tid;  // < 746496 exactly
    float v;
    if (j < 65536) v = c2w[j];
    else if (j < 91136) v = c3w[j - 65536];
    else if (j < 156672) v = qw[j - 91136];
    else if (j < 222208) v = pw[j - 156672];
    else if (j < 484352) v = f1w[j - 222208];
    else v = f2w[j - 484352];
    wbz[j] = f2bf(v);
  }
}

// conv1 v9: best-known. 1024-thr (16-wave) block, 1/CU, 4 waves/SIMD via
// __launch_bounds__(1024,4). 32x32 MFMA, wave = 1 row x 64 px x 64 co
// (AI 32). Measured ~310us, MfmaUtil 63, occupancy ~45%. Plateau at AI 32.
__global__ __launch_bounds__(1024, 4) void conv1_mfma(const bf16_t* __restrict__ xtb,
                                                      const bf16_t* __restrict__ wtb,
                                                      const float* __restrict__ bias,
                                                      bf16_t* __restrict__ h1) {
  int bid = blockIdx.x;
  int cq = bid & 3;            // W-slice phase, XCD-aligned
  int rem = bid >> 2;          // 0..63
  int bt = rem & 15;
  int rb = rem >> 4;           // 0..3 : 16-row band
  int r0 = rb * 16;
  int co0 = cq * 64;
  int tid = threadIdx.x;
  int wv = tid >> 6;           // 0..15
  int lane = tid & 63;
  int l31 = lane & 31;
  int h = lane >> 5;           // 0..1 : k-half
  __shared__ __align__(16) short As[22][4][70][8];    // 98,560 B
  __shared__ __align__(16) short Ws[2][7][4][64][8];  // 57,344 B
  {
    s16x8 z = {0, 0, 0, 0, 0, 0, 0, 0};
    for (int i = tid; i < 22 * 4 * 70; i += 1024) *(s16x8*)((short*)As + i * 8) = z;
  }
  __syncthreads();
  f32x16 acc[2][2] = {};       // [mt][nt] 32x32 tiles
  const bf16_t* xb = xtb + (size_t)bt * (NN * CC);
  for (int cig = 0; cig < 8; ++cig) {
    int ci0 = cig * 32;
    // stage As: 22 rows x 4 ci-subgroups (halo rows outside image stay zero)
    for (int t = wv; t < 88; t += 16) {
      int rr = t >> 2, go = t & 3;
      int r = r0 - 3 + rr;
      if (r >= 0 && r < HH) {
        const bf16_t* gsrc = xb + ((size_t)(r * 64 + lane)) * CC + ci0 + go * 8;
        g2l16(gsrc, &As[rr][go][3][0]);
      }
    }
    // stage Ws buf0, ky=0
    {
      const bf16_t* wk = wtb + ((size_t)((0 * 8 + cig) * 4 + cq)) * (1792 * 8);
      for (int t = wv; t < 28; t += 16)
        g2l16(wk + (size_t)t * 512 + lane * 8, (short*)Ws[0] + t * 512);
    }
    __syncthreads();
    for (int ky = 0; ky < 7; ++ky) {
      int cur = ky & 1;
      if (ky < 6) {  // prefetch next ky's W taps into the other buffer
        const bf16_t* wk = wtb + ((size_t)(((ky + 1) * 8 + cig) * 4 + cq)) * (1792 * 8);
        for (int t = wv; t < 28; t += 16)
          g2l16(wk + (size_t)t * 512 + lane * 8, (short*)Ws[cur ^ 1] + t * 512);
      }
#pragma unroll
      for (int kx = 0; kx < 7; ++kx) {
        s16x8 fa[2][2], fb[2][2];  // [mt|nt][ks]
#pragma unroll
        for (int mt = 0; mt < 2; ++mt)
#pragma unroll
          for (int ks = 0; ks < 2; ++ks) {
            fa[mt][ks] = *(const s16x8*)&As[wv + ky][ks * 2 + h][mt * 32 + l31 + kx][0];
            fb[mt][ks] = *(const s16x8*)&Ws[cur][kx][ks * 2 + h][mt * 32 + l31][0];
          }
#pragma unroll
        for (int ks = 0; ks < 2; ++ks)
#pragma unroll
          for (int mt = 0; mt < 2; ++mt)
#pragma unroll
            for (int nt = 0; nt < 2; ++nt)
              acc[mt][nt] = __builtin_amdgcn_mfma_f32_32x32x16_bf16(
                  fa[mt][ks], fb[nt][ks], acc[mt][nt], 0, 0, 0);
      }
      __syncthreads();  // drains vmcnt: next Ws buffer ready; readers done
    }
  }
  int row = r0 + wv;
  const size_t xbase = (size_t)bt * (NN * CC);
#pragma unroll
  for (int nt = 0; nt < 2; ++nt) {
    int co = co0 + nt * 32 + l31;
    float bs = bias[co];
#pragma unroll
    for (int mt = 0; mt < 2; ++mt) {
#pragma unroll
      for (int rg = 0; rg < 16; ++rg) {
        int px = mt * 32 + (rg & 3) + 8 * (rg >> 2) + 4 * h;
        float vv = acc[mt][nt][rg] + bs;
        h1[xbase + (size_t)(row * 64 + px) * CC + co] = f2bf(gelu_f(vv));
      }
    }
  }
}

// conv23 v13: fused conv2(gelu) -> conv3 (unchanged).
__global__ __launch_bounds__(512) void conv23(const bf16_t* __restrict__ bh1,
                                              const bf16_t* __restrict__ w2,
                                              const float* __restrict__ b2,
                                              const bf16_t* __restrict__ w3,
                                              bf16_t* __restrict__ czt) {
  __shared__ __align__(16) char smem[126720];
  short (*As2)[72] = (short(*)[72])smem;
  short (*Bs2)[72] = (short(*)[72])(smem + 18432);
  short (*h2s)[264] = (short(*)[264])smem;
  short (*w3s)[264] = (short(*)[264])(smem + 67584);
  short (*ot)[132] = (short(*)[132])smem;
  int tid = threadIdx.x;
  int m0 = blockIdx.x * 128;
  int lane = tid & 63, wv = tid >> 6;
  int wm = wv & 1, wn = wv >> 1;
  int lm = lane & 15, g = lane >> 4;
  f32x4 acc[4][4] = {};
  int r1 = tid >> 2, kq = tid & 3;
  int br = tid >> 1, bq = (tid & 1) * 32;
  for (int k0 = 0; k0 < 256; k0 += 64) {
    *(s16x8*)&As2[r1][kq * 8] =
        *(const s16x8*)(bh1 + (size_t)(m0 + r1) * 256 + k0 + kq * 8);
    *(s16x8*)&As2[r1][32 + kq * 8] =
        *(const s16x8*)(bh1 + (size_t)(m0 + r1) * 256 + k0 + 32 + kq * 8);
#pragma unroll
    for (int j = 0; j < 4; ++j)
      *(s16x8*)&Bs2[br][bq + j * 8] =
          *(const s16x8*)(w2 + (size_t)br * 256 + k0 + bq + j * 8);
    __syncthreads();
#pragma unroll
    for (int ks = 0; ks < 2; ++ks) {
      s16x8 af[4], bf[4];
#pragma unroll
      for (int mt = 0; mt < 4; ++mt)
        af[mt] = *(const s16x8*)&As2[wm * 64 + mt * 16 + lm][ks * 32 + g * 8];
#pragma unroll
      for (int nt = 0; nt < 4; ++nt)
        bf[nt] = *(const s16x8*)&Bs2[wn * 64 + nt * 16 + lm][ks * 32 + g * 8];
#pragma unroll
      for (int mt = 0; mt < 4; ++mt)
#pragma unroll
        for (int nt = 0; nt < 4; ++nt)
          acc[mt][nt] = __builtin_amdgcn_mfma_f32_16x16x32_bf16(af[mt], bf[nt],
                                                                acc[mt][nt], 0, 0, 0);
    }
    __syncthreads();
  }
#pragma unroll
  for (int nt = 0; nt < 4; ++nt) {
    int c = wn * 64 + nt * 16 + lm;
    float bs = b2[c];
#pragma unroll
    for (int mt = 0; mt < 4; ++mt) {
#pragma unroll
      for (int rg = 0; rg < 4; ++rg) {
        int m = wm * 64 + mt * 16 + g * 4 + rg;
        h2s[m][c] = (short)f2bf(gelu_f(acc[mt][nt][rg] + bs));
      }
    }
  }
  {
    s16x8 z = {0, 0, 0, 0, 0, 0, 0, 0};
    for (int t = tid; t < 112 * 32; t += 512) {
      int rr = t >> 5, cc = (t & 31) * 8;
      s16x8 vv = z;
      if (rr < 100) vv = *(const s16x8*)(w3 + (size_t)rr * 256 + cc);
      *(s16x8*)&w3s[rr][cc] = vv;
    }
  }
  __syncthreads();
  f32x4 acc3[4][2] = {};
  int n_base = wn * 32;
#pragma unroll
  for (int k0 = 0; k0 < 256; k0 += 32) {
    s16x8 af[4], bf[2];
#pragma unroll
    for (int mt = 0; mt < 4; ++mt)
      af[mt] = *(const s16x8*)&h2s[wm * 64 + mt * 16 + lm][k0 + g * 8];
#pragma unroll
    for (int nt = 0; nt < 2; ++nt)
      bf[nt] = *(const s16x8*)&w3s[n_base + nt * 16 + lm][k0 + g * 8];
#pragma unroll
    for (int mt = 0; mt < 4; ++mt)
#pragma unroll
      for (int nt = 0; nt < 2; ++nt)
        acc3[mt][nt] = __builtin_amdgcn_mfma_f32_16x16x32_bf16(af[mt], bf[nt],
                                                               acc3[mt][nt], 0, 0, 0);
  }
  __syncthreads();
#pragma unroll
  for (int nt = 0; nt < 2; ++nt) {
    int kc = n_base + nt * 16 + lm;
    if (kc < 100) {
#pragma unroll
      for (int mt = 0; mt < 4; ++mt) {
#pragma unroll
        for (int rg = 0; rg < 4; ++rg) {
          int px = wm * 64 + mt * 16 + g * 4 + rg;
          ot[kc][px] = (short)f2bf(acc3[mt][nt][rg]);
        }
      }
    }
  }
  __syncthreads();
  for (int t = tid; t < 100 * 128; t += 512) {
    int kc = t >> 7, px = t & 127;
    czt[(size_t)kc * 65536 + m0 + px] = (bf16_t)ot[kc][px];
  }
}

// bf16 MFMA GEMM, K-step 64 (v12)
template <int GELU, int BIAS, int TOUT, int OBF>
__global__ __launch_bounds__(256) void gemm_mfma(const bf16_t* __restrict__ A,
                                                 const bf16_t* __restrict__ W,
                                                 const float* __restrict__ bias,
                                                 void* __restrict__ outp,
                                                 int M, int N, int K, int ldo,
                                                 size_t aStr, size_t oStr) {
  __shared__ short As[128][72];
  __shared__ short Bs[128][72];
  A += (size_t)blockIdx.z * aStr;
  size_t obase = (size_t)blockIdx.z * oStr;
  int tid = threadIdx.x;
  int n0 = blockIdx.x * 128, m0 = blockIdx.y * 128;
  int lane = tid & 63, wv = tid >> 6;
  int wm = wv & 1, wn = wv >> 1;
  int lm = lane & 15, g = lane >> 4;
  f32x4 acc[4][4] = {};
  int r1 = tid >> 2, kq = tid & 3;
  int r2 = r1 + 64;
  for (int k0 = 0; k0 < K; k0 += 64) {
    *(s16x8*)&As[r1][kq * 8] = *(const s16x8*)(A + (size_t)(m0 + r1) * K + k0 + kq * 8);
    *(s16x8*)&As[r1][32 + kq * 8] =
        *(const s16x8*)(A + (size_t)(m0 + r1) * K + k0 + 32 + kq * 8);
    *(s16x8*)&As[r2][kq * 8] = *(const s16x8*)(A + (size_t)(m0 + r2) * K + k0 + kq * 8);
    *(s16x8*)&As[r2][32 + kq * 8] =
        *(const s16x8*)(A + (size_t)(m0 + r2) * K + k0 + 32 + kq * 8);
    s16x8 z = {0, 0, 0, 0, 0, 0, 0, 0};
    s16x8 b1 = z, b2 = z, b3 = z, b4 = z;
    if (n0 + r1 < N) {
      b1 = *(const s16x8*)(W + (size_t)(n0 + r1) * K + k0 + kq * 8);
      b2 = *(const s16x8*)(W + (size_t)(n0 + r1) * K + k0 + 32 + kq * 8);
    }
    if (n0 + r2 < N) {
      b3 = *(const s16x8*)(W + (size_t)(n0 + r2) * K + k0 + kq * 8);
      b4 = *(const s16x8*)(W + (size_t)(n0 + r2) * K + k0 + 32 + kq * 8);
    }
    *(s16x8*)&Bs[r1][kq * 8] = b1;
    *(s16x8*)&Bs[r1][32 + kq * 8] = b2;
    *(s16x8*)&Bs[r2][kq * 8] = b3;
    *(s16x8*)&Bs[r2][32 + kq * 8] = b4;
    __syncthreads();
#pragma unroll
    for (int ks = 0; ks < 2; ++ks) {
      s16x8 af[4], bf[4];
#pragma unroll
      for (int mt = 0; mt < 4; ++mt)
        af[mt] = *(const s16x8*)&As[wm * 64 + mt * 16 + lm][ks * 32 + g * 8];
#pragma unroll
      for (int nt = 0; nt < 4; ++nt)
        bf[nt] = *(const s16x8*)&Bs[wn * 64 + nt * 16 + lm][ks * 32 + g * 8];
#pragma unroll
      for (int mt = 0; mt < 4; ++mt)
#pragma unroll
        for (int nt = 0; nt < 4; ++nt)
          acc[mt][nt] = __builtin_amdgcn_mfma_f32_16x16x32_bf16(af[mt], bf[nt],
                                                                acc[mt][nt], 0, 0, 0);
    }
    __syncthreads();
  }
#pragma unroll
  for (int nt = 0; nt < 4; ++nt) {
    int n = n0 + wn * 64 + nt * 16 + lm;
    if (n >= N) continue;
    float bs = BIAS ? bias[n] : 0.f;
#pragma unroll
    for (int mt = 0; mt < 4; ++mt) {
#pragma unroll
      for (int rg = 0; rg < 4; ++rg) {
        int m = m0 + wm * 64 + mt * 16 + g * 4 + rg;
        float v = acc[mt][nt][rg] + bs;
        if (GELU) v = gelu_f(v);
        size_t idx = obase + (TOUT ? ((size_t)n * ldo + m) : ((size_t)m * ldo + n));
        if (OBF)
          ((bf16_t*)outp)[idx] = f2bf(v);
        else
          ((float*)outp)[idx] = v;
      }
    }
  }
}

// gemm_ln v16: BM 128 -> 64 so the grid fills all 256 CUs (v14 ran 128
// blocks = half-GPU). 64 rows x full N=256 per block, 8 waves 1x8
// (wave = 64 rows x 32 cols, acc[4][2]); single-phase LN epilogue
// (Ls[64][260] f32 = 66.5KB, aliases dead As/Bs). Reduction order ==
// add_ln v12. A/dst_b alias (obz==outb_b) safe: block reads only rows
// [m0,m0+64) before the epilogue and writes exactly those rows.
template <int WB>
__global__ __launch_bounds__(512) void gemm_ln(const bf16_t* __restrict__ A,
                                               const bf16_t* __restrict__ W,
                                               const float* __restrict__ bias,
                                               const float* __restrict__ lnw,
                                               const float* __restrict__ lnb,
                                               const float* __restrict__ res,
                                               float* __restrict__ dst,
                                               bf16_t* __restrict__ dst_b,
                                               int K, size_t aStr, size_t oStr) {
  __shared__ __align__(16) char smem[66560];
  short (*As)[72] = (short(*)[72])smem;            // 64 rows: 9,216 B
  short (*Bs)[72] = (short(*)[72])(smem + 9216);   // 256 rows: 36,864 B
  float (*Ls)[260] = (float(*)[260])smem;          // 66,560 B (epilogue)
  int tid = threadIdx.x;
  int m0 = blockIdx.x * 64;
  A += (size_t)blockIdx.y * aStr;
  size_t obase = (size_t)blockIdx.y * oStr;
  int lane = tid & 63, wv = tid >> 6;              // 8 waves, wave = n-tile
  int lm = lane & 15, g = lane >> 4;
  f32x4 acc[4][2] = {};
  int r1 = tid >> 3, kq = tid & 7;                 // A: 64 rows x 8 chunks
  int br = tid >> 1, bq = (tid & 1) * 32;          // B: 256 rows x 2 halves
  for (int k0 = 0; k0 < K; k0 += 64) {
    *(s16x8*)&As[r1][kq * 8] = *(const s16x8*)(A + (size_t)(m0 + r1) * K + k0 + kq * 8);
#pragma unroll
    for (int j = 0; j < 4; ++j)
      *(s16x8*)&Bs[br][bq + j * 8] =
          *(const s16x8*)(W + (size_t)br * K + k0 + bq + j * 8);
    __syncthreads();
#pragma unroll
    for (int ks = 0; ks < 2; ++ks) {
      s16x8 af[4], bf[2];
#pragma unroll
      for (int mt = 0; mt < 4; ++mt)
        af[mt] = *(const s16x8*)&As[mt * 16 + lm][ks * 32 + g * 8];
#pragma unroll
      for (int nt = 0; nt < 2; ++nt)
        bf[nt] = *(const s16x8*)&Bs[wv * 32 + nt * 16 + lm][ks * 32 + g * 8];
#pragma unroll
      for (int mt = 0; mt < 4; ++mt)
#pragma unroll
        for (int nt = 0; nt < 2; ++nt)
          acc[mt][nt] = __builtin_amdgcn_mfma_f32_16x16x32_bf16(af[mt], bf[nt],
                                                                acc[mt][nt], 0, 0, 0);
    }
    __syncthreads();
  }
  // single-phase LN epilogue: stage all 64 rows x 256 cols + bias to Ls
#pragma unroll
  for (int nt = 0; nt < 2; ++nt) {
    int c = wv * 32 + nt * 16 + lm;
    float bs = bias[c];
#pragma unroll
    for (int mt = 0; mt < 4; ++mt) {
#pragma unroll
      for (int rg = 0; rg < 4; ++rg) {
        int m = mt * 16 + g * 4 + rg;
        Ls[m][c] = acc[mt][nt][rg] + bs;  // bank (4m+c)%32: 2-way, free
      }
    }
  }
  __syncthreads();
#pragma unroll
  for (int i = 0; i < 8; ++i) {
    int mr = wv * 8 + i;
    size_t grow = (size_t)(m0 + mr);
    int c = lane * 4;
    float4 v = *(const float4*)&Ls[mr][c];
    float s = v.x + v.y + v.z + v.w;
#pragma unroll
    for (int off = 32; off; off >>= 1) s += __shfl_xor(s, off, 64);
    float mmean = s * (1.f / CC);
    float d0 = v.x - mmean, d1 = v.y - mmean, d2 = v.z - mmean, d3 = v.w - mmean;
    float q = d0 * d0 + d1 * d1 + d2 * d2 + d3 * d3;
#pragma unroll
    for (int off = 32; off; off >>= 1) q += __shfl_xor(q, off, 64);
    float inv = rsqrtf(q * (1.f / CC) + 1e-5f);
    float4 r4 = *(const float4*)&res[obase + grow * CC + c];
    float4 lw = *(const float4*)&lnw[c];
    float4 lb = *(const float4*)&lnb[c];
    float4 o;
    o.x = r4.x + d0 * inv * lw.x + lb.x;
    o.y = r4.y + d1 * inv * lw.y + lb.y;
    o.z = r4.z + d2 * inv * lw.z + lb.z;
    o.w = r4.w + d3 * inv * lw.w + lb.w;
    *(float4*)&dst[obase + grow * CC + c] = o;
    if (WB) {
      ushort4 ob;
      ob.x = f2bf(o.x); ob.y = f2bf(o.y); ob.z = f2bf(o.z); ob.w = f2bf(o.w);
      *(ushort4*)&dst_b[obase + grow * CC + c] = ob;
    }
  }
}

// fused k/v projections: z=0 -> k, z=1 -> v. M=400, N=256, K=256.
__global__ __launch_bounds__(256) void gemm_kv(const float* __restrict__ cin,
                                               const float* __restrict__ kw,
                                               const float* __restrict__ kbias,
                                               const float* __restrict__ vw,
                                               const float* __restrict__ vbias,
                                               float* __restrict__ kout,
                                               float* __restrict__ vout) {
  const float* Wm = blockIdx.z ? vw : kw;
  const float* bias = blockIdx.z ? vbias : kbias;
  float* outp = blockIdx.z ? vout : kout;
  const int M = 400, N = 256, K = 256;
  __shared__ float As[16][68];
  __shared__ float Ws[16][68];
  int tid = threadIdx.x;
  int n0 = blockIdx.x * 64, m0 = blockIdx.y * 64;
  int txn = tid & 15, tym = tid >> 4;
  int mi = tid >> 2, kq = (tid & 3) * 4;
  float acc[4][4] = {};
  for (int k0 = 0; k0 < K; k0 += 16) {
    float4 av = {0, 0, 0, 0}, wvv = {0, 0, 0, 0};
    if (m0 + mi < M) av = *(const float4*)&cin[(size_t)(m0 + mi) * K + k0 + kq];
    if (n0 + mi < N) wvv = *(const float4*)&Wm[(size_t)(n0 + mi) * K + k0 + kq];
    As[kq + 0][mi] = av.x; As[kq + 1][mi] = av.y; As[kq + 2][mi] = av.z; As[kq + 3][mi] = av.w;
    Ws[kq + 0][mi] = wvv.x; Ws[kq + 1][mi] = wvv.y; Ws[kq + 2][mi] = wvv.z; Ws[kq + 3][mi] = wvv.w;
    __syncthreads();
#pragma unroll
    for (int ki = 0; ki < 16; ++ki) {
      float4 a4 = *(const float4*)&As[ki][tym * 4];
      float4 w4 = *(const float4*)&Ws[ki][txn * 4];
      float am[4] = {a4.x, a4.y, a4.z, a4.w};
      float wn[4] = {w4.x, w4.y, w4.z, w4.w};
#pragma unroll
      for (int i = 0; i < 4; ++i)
#pragma unroll
        for (int j = 0; j < 4; ++j) acc[i][j] += am[i] * wn[j];
    }
    __syncthreads();
  }
#pragma unroll
  for (int i = 0; i < 4; ++i) {
    int m = m0 + tym * 4 + i;
    if (m >= M) continue;
#pragma unroll
    for (int j = 0; j < 4; ++j) {
      int n = n0 + txn * 4 + j;
      outp[(size_t)m * 256 + n] = acc[i][j] + bias[n];
    }
  }
}

// 1600 rows of 4096 bf16, softmax in place; thread owns 16 contiguous elems
__global__ __launch_bounds__(256) void softmax_rows(bf16_t* __restrict__ p) {
  __shared__ float sh[8];
  int tid = threadIdx.x;
  bf16_t* base = p + (size_t)blockIdx.x * NN + tid * 16;
  s16x8 a = *(const s16x8*)base;
  s16x8 b = *(const s16x8*)(base + 8);
  float vals[16];
#pragma unroll
  for (int j = 0; j < 8; ++j) {
    vals[j] = bf2f((bf16_t)a[j]);
    vals[8 + j] = bf2f((bf16_t)b[j]);
  }
  float mx = -1e30f;
#pragma unroll
  for (int j = 0; j < 16; ++j) mx = fmaxf(mx, vals[j]);
#pragma unroll
  for (int off = 32; off; off >>= 1) mx = fmaxf(mx, __shfl_xor(mx, off, 64));
  if ((tid & 63) == 0) sh[tid >> 6] = mx;
  __syncthreads();
  mx = fmaxf(fmaxf(sh[0], sh[1]), fmaxf(sh[2], sh[3]));
  float s = 0.f;
#pragma unroll
  for (int j = 0; j < 16; ++j) {
    vals[j] = expf(vals[j] - mx);
    s += vals[j];
  }
#pragma unroll
  for (int off = 32; off; off >>= 1) s += __shfl_xor(s, off, 64);
  if ((tid & 63) == 0) sh[4 + (tid >> 6)] = s;
  __syncthreads();
  s = sh[4] + sh[5] + sh[6] + sh[7];
  float inv = 1.f / s;
  s16x8 oa, ob;
#pragma unroll
  for (int j = 0; j < 8; ++j) {
    oa[j] = (short)f2bf(vals[j] * inv);
    ob[j] = (short)f2bf(vals[8 + j] * inv);
  }
  *(s16x8*)base = oa;
  *(s16x8*)(base + 8) = ob;
}

// center via MFMA split-K (8 chunks of 512): partial[nc][bt][kc][c].
__global__ __launch_bounds__(256) void center_mfma(const bf16_t* __restrict__ soft,
                                                   const bf16_t* __restrict__ xtb,
                                                   float* __restrict__ partial) {
  int c0 = blockIdx.x * 128;
  int bt = blockIdx.y;
  int nc = blockIdx.z;
  int tid = threadIdx.x;
  int lane = tid & 63, wv = tid >> 6;
  int wm = wv & 1, wn = wv >> 1;
  int lm = lane & 15, g = lane >> 4;
  __shared__ short As[128][40];
  __shared__ short Bs[128][40];
  f32x4 acc[4][4] = {};
  int r1 = tid >> 2, kq = tid & 3;
  int r2 = r1 + 64;
  int bk = tid & 31, bc = (tid >> 5) * 16;
  const bf16_t* sb = soft + (size_t)bt * NN + (size_t)nc * 512;
  const bf16_t* xb = xtb + ((size_t)bt * NN + (size_t)nc * 512) * CC + c0;
  for (int k0 = 0; k0 < 512; k0 += 32) {
    *(s16x8*)&As[r1][kq * 8] =
        *(const s16x8*)(sb + (size_t)r1 * (BT * NN) + k0 + kq * 8);
    if (r2 < KCC)
      *(s16x8*)&As[r2][kq * 8] =
          *(const s16x8*)(sb + (size_t)r2 * (BT * NN) + k0 + kq * 8);
    s16x8 v0 = *(const s16x8*)(xb + (size_t)(k0 + bk) * CC + bc);
    s16x8 v1 = *(const s16x8*)(xb + (size_t)(k0 + bk) * CC + bc + 8);
#pragma unroll
    for (int j = 0; j < 8; ++j) Bs[bc + j][bk] = v0[j];
#pragma unroll
    for (int j = 0; j < 8; ++j) Bs[bc + 8 + j][bk] = v1[j];
    __syncthreads();
    s16x8 af[4], bf[4];
#pragma unroll
    for (int mt = 0; mt < 4; ++mt)
      af[mt] = *(const s16x8*)&As[wm * 64 + mt * 16 + lm][g * 8];
#pragma unroll
    for (int nt = 0; nt < 4; ++nt)
      bf[nt] = *(const s16x8*)&Bs[wn * 64 + nt * 16 + lm][g * 8];
#pragma unroll
    for (int mt = 0; mt < 4; ++mt)
#pragma unroll
      for (int nt = 0; nt < 4; ++nt)
        acc[mt][nt] = __builtin_amdgcn_mfma_f32_16x16x32_bf16(af[mt], bf[nt],
                                                              acc[mt][nt], 0, 0, 0);
    __syncthreads();
  }
  size_t obase = ((size_t)nc * BT + bt) * (KCC * CC);
#pragma unroll
  for (int nt = 0; nt < 4; ++nt) {
    int c = c0 + wn * 64 + nt * 16 + lm;
#pragma unroll
    for (int mt = 0; mt < 4; ++mt) {
#pragma unroll
      for (int rg = 0; rg < 4; ++rg) {
        int m = wm * 64 + mt * 16 + g * 4 + rg;
        if (m < KCC) partial[obase + (size_t)m * CC + c] = acc[mt][nt][rg];
      }
    }
  }
}

// cosine-sim gating + LN -> cin[b][kc][c]. v13 batched reductions.
__global__ __launch_bounds__(256) void sim_cin(const float* __restrict__ partial,
                                               const float* __restrict__ alpha_p,
                                               const float* __restrict__ beta_p,
                                               const float* __restrict__ lnw,
                                               const float* __restrict__ lnb,
                                               float* __restrict__ cin) {
  int b = blockIdx.x / KCC, kc = blockIdx.x % KCC;
  int c = threadIdx.x;
  float p0 = 0.f, p1 = 0.f, p2 = 0.f, lst = 0.f;
#pragma unroll
  for (int nc = 0; nc < 8; ++nc) {
    size_t base = ((size_t)nc * BT) * KCC * CC;
    p0 += partial[base + ((size_t)(b * 4 + 0) * KCC + kc) * CC + c];
    p1 += partial[base + ((size_t)(b * 4 + 1) * KCC + kc) * CC + c];
    p2 += partial[base + ((size_t)(b * 4 + 2) * KCC + kc) * CC + c];
    lst += partial[base + ((size_t)(b * 4 + 3) * KCC + kc) * CC + c];
  }
  float v7[7] = {lst * lst, p0 * p0, p1 * p1, p2 * p2,
                 lst * p0, lst * p1, lst * p2};
#pragma unroll
  for (int off = 32; off; off >>= 1)
#pragma unroll
    for (int j = 0; j < 7; ++j) v7[j] += __shfl_xor(v7[j], off, 64);
  __shared__ float sh7[4][8];
  if ((threadIdx.x & 63) == 0)
#pragma unroll
    for (int j = 0; j < 7; ++j) sh7[threadIdx.x >> 6][j] = v7[j];
  __syncthreads();
  float s7[7];
#pragma unroll
  for (int j = 0; j < 7; ++j)
    s7[j] = sh7[0][j] + sh7[1][j] + sh7[2][j] + sh7[3][j];
  float ll = s7[0], q0 = s7[1], q1 = s7[2], q2 = s7[3];
  float d0 = s7[4], d1 = s7[5], d2 = s7[6];
  float alpha = alpha_p[0], beta = beta_p[0];
  float nl = sqrtf(ll);
  float c0 = 1.f / (1.f + expf(-(beta + alpha * (d0 / fmaxf(nl * sqrtf(q0), 1e-8f)))));
  float c1 = 1.f / (1.f + expf(-(beta + alpha * (d1 / fmaxf(nl * sqrtf(q1), 1e-8f)))));
  float c2 = 1.f / (1.f + expf(-(beta + alpha * (d2 / fmaxf(nl * sqrtf(q2), 1e-8f)))));
  float v = lst + c0 * p0 + c1 * p1 + c2 * p2;
  float m = block_sum256(v) * (1.f / CC);
  float dv = v - m;
  float var = block_sum256(dv * dv) * (1.f / CC);
  cin[((size_t)b * KCC + kc) * CC + c] = dv * rsqrtf(var + 1e-5f) * lnw[c] + lnb[c];
}

// attention v16: QK remapped to thread=(head hg, kcl) so each thread reads
// only its head's 32-d slice of the K row (8x fewer Ks LDS reads; the old
// (nn,kcl) map read the whole 256-d row per thread with 8x cross-thread
// redundancy). qs reads become wave-broadcast (2 addrs/wave ~ free).
// Ks pad 257->260 for 16B-aligned float4 rows. Softmax + PV unchanged.
__global__ __launch_bounds__(256) void attn2(const float* __restrict__ q,
                                             const float* __restrict__ kb,
                                             const float* __restrict__ vb,
                                             bf16_t* __restrict__ ob) {
  int b = blockIdx.y;
  int n0 = blockIdx.x * 8;
  int tid = threadIdx.x;
  __shared__ float qs[8][256];
  __shared__ float Ks[32][260];
  __shared__ float sc[8][8][104];
#pragma unroll
  for (int r = 0; r < 8; ++r)
    qs[r][tid] = q[((size_t)b * NN + n0 + r) * CC + tid] * 0.17677669529663687f;
  int hg = tid >> 5, kcl = tid & 31;
  for (int kt = 0; kt < 4; ++kt) {
    int kbase = kt * 32;
    int rows = (kbase + 32 <= KCC) ? 32 : (KCC - kbase);
    __syncthreads();
    for (int idx = tid; idx < rows * 256; idx += 256) {
      int rr = idx >> 8, cc = idx & 255;
      Ks[rr][cc] = kb[((size_t)b * KCC + kbase + rr) * CC + cc];
    }
    __syncthreads();
    if (kcl < rows) {
      float4 kv[8];
#pragma unroll
      for (int dq = 0; dq < 8; ++dq)
        kv[dq] = *(const float4*)&Ks[kcl][hg * HDD + dq * 4];
#pragma unroll
      for (int nn = 0; nn < 8; ++nn) {
        float s = 0.f;
#pragma unroll
        for (int dq = 0; dq < 8; ++dq) {
          float4 qv = *(const float4*)&qs[nn][hg * HDD + dq * 4];
          s += qv.x * kv[dq].x + qv.y * kv[dq].y + qv.z * kv[dq].z + qv.w * kv[dq].w;
        }
        sc[nn][hg][kbase + kcl] = s;
      }
    }
  }
  __syncthreads();
  {
    int tnn = tid >> 5, th = (tid >> 2) & 7, j = tid & 3;
    float mx = -1e30f;
    for (int kc = j * 25; kc < j * 25 + 25; ++kc) mx = fmaxf(mx, sc[tnn][th][kc]);
    mx = fmaxf(mx, __shfl_xor(mx, 1, 64));
    mx = fmaxf(mx, __shfl_xor(mx, 2, 64));
    float sm = 0.f;
    for (int kc = j * 25; kc < j * 25 + 25; ++kc) {
      float e = expf(sc[tnn][th][kc] - mx);
      sc[tnn][th][kc] = e;
      sm += e;
    }
    sm += __shfl_xor(sm, 1, 64);
    sm += __shfl_xor(sm, 2, 64);
    float inv = 1.f / sm;
    for (int kc = j * 25; kc < j * 25 + 25; ++kc) sc[tnn][th][kc] *= inv;
  }
  __syncthreads();
  float o[8] = {0, 0, 0, 0, 0, 0, 0, 0};
  int h = tid >> 5;
  for (int kc = 0; kc < KCC; ++kc) {
    float v = vb[((size_t)b * KCC + kc) * CC + tid];
#pragma unroll
    for (int r = 0; r < 8; ++r) o[r] += sc[r][h][kc] * v;
  }
#pragma unroll
  for (int r = 0; r < 8; ++r)
    ob[((size_t)b * NN + n0 + r) * CC + tid] = f2bf(o[r]);
}

// dwconv v14: sliding-window rows. block = 16-px row segment (grid 1024),
// 3-col register window rotated along w: ~3.4 loads/px vs 9.
__global__ __launch_bounds__(256) void dwconv_kernel(const bf16_t* __restrict__ y1,
                                                     const float* __restrict__ dww,
                                                     const float* __restrict__ dwb,
                                                     bf16_t* __restrict__ y2) {
  int t = blockIdx.x;          // b(4) x h(64) x quarter(4)
  int b = t >> 8;
  int h = (t >> 2) & 63;
  int qd = t & 3;
  int w0 = qd << 4;
  int c40 = threadIdx.x * 4;
  float wreg[4][9];
#pragma unroll
  for (int j = 0; j < 4; ++j)
#pragma unroll
    for (int k = 0; k < 9; ++k) wreg[j][k] = dww[(size_t)(c40 + j) * 9 + k];
  float b4[4];
#pragma unroll
  for (int j = 0; j < 4; ++j) b4[j] = dwb[c40 + j];
  const bf16_t* bb = y1 + (size_t)b * NN * C4 + c40;
  bf16_t* obp = y2 + (size_t)b * NN * C4 + c40;
  ushort4 z4; z4.x = 0; z4.y = 0; z4.z = 0; z4.w = 0;
  bool rok[3];
  size_t rbase[3];
#pragma unroll
  for (int dy = 0; dy < 3; ++dy) {
    int r = h - 1 + dy;
    rok[dy] = (r >= 0 && r < HH);
    rbase[dy] = (size_t)(rok[dy] ? r : 0) * 64 * C4;
  }
  ushort4 u0[3], u1[3], u2[3];
#pragma unroll
  for (int dy = 0; dy < 3; ++dy) {
    u0[dy] = (rok[dy] && w0 > 0) ? *(const ushort4*)(bb + rbase[dy] + (size_t)(w0 - 1) * C4) : z4;
    u1[dy] = rok[dy] ? *(const ushort4*)(bb + rbase[dy] + (size_t)w0 * C4) : z4;
  }
  for (int w = w0; w < w0 + 16; ++w) {
    bool cok = (w + 1 < 64);
#pragma unroll
    for (int dy = 0; dy < 3; ++dy)
      u2[dy] = (rok[dy] && cok) ? *(const ushort4*)(bb + rbase[dy] + (size_t)(w + 1) * C4) : z4;
    float acc0 = 0.f, acc1 = 0.f, acc2 = 0.f, acc3 = 0.f;
#pragma unroll
    for (int dy = 0; dy < 3; ++dy) {
      acc0 += bf2f(u0[dy].x) * wreg[0][dy * 3 + 0] + bf2f(u1[dy].x) * wreg[0][dy * 3 + 1] +
              bf2f(u2[dy].x) * wreg[0][dy * 3 + 2];
      acc1 += bf2f(u0[dy].y) * wreg[1][dy * 3 + 0] + bf2f(u1[dy].y) * wreg[1][dy * 3 + 1] +
              bf2f(u2[dy].y) * wreg[1][dy * 3 + 2];
      acc2 += bf2f(u0[dy].z) * wreg[2][dy * 3 + 0] + bf2f(u1[dy].z) * wreg[2][dy * 3 + 1] +
              bf2f(u2[dy].z) * wreg[2][dy * 3 + 2];
      acc3 += bf2f(u0[dy].w) * wreg[3][dy * 3 + 0] + bf2f(u1[dy].w) * wreg[3][dy * 3 + 1] +
              bf2f(u2[dy].w) * wreg[3][dy * 3 + 2];
    }
    ushort4 o;
    o.x = f2bf(gelu_f(acc0 + b4[0]));
    o.y = f2bf(gelu_f(acc1 + b4[1]));
    o.z = f2bf(gelu_f(acc2 + b4[2]));
    o.w = f2bf(gelu_f(acc3 + b4[3]));
    *(ushort4*)(obp + (size_t)(h * 64 + w) * C4) = o;
#pragma unroll
    for (int dy = 0; dy < 3; ++dy) {
      u0[dy] = u1[dy];
      u1[dy] = u2[dy];
    }
  }
}

extern "C" void kernel_launch(void* const* d_in, const int* in_sizes, int n_in,
                              void* d_out, int out_size, void* d_ws, size_t ws_size,
                              hipStream_t stream) {
  const float* x = (const float*)d_in[0];
  const float* mem = (const float*)d_in[1];
  const float* conv1_w = (const float*)d_in[2];
  const float* conv1_b = (const float*)d_in[3];
  const float* conv2_w = (const float*)d_in[4];
  const float* conv2_b = (const float*)d_in[5];
  const float* conv3_w = (const float*)d_in[6];
  const float* sim_a = (const float*)d_in[7];
  const float* sim_b = (const float*)d_in[8];
  const float* ln_w = (const float*)d_in[9];
  const float* ln_b = (const float*)d_in[10];
  const float* q_w = (const float*)d_in[11];
  const float* q_b = (const float*)d_in[12];
  const float* k_w = (const float*)d_in[13];
  const float* k_b = (const float*)d_in[14];
  const float* v_w = (const float*)d_in[15];
  const float* v_b = (const float*)d_in[16];
  const float* proj_w = (const float*)d_in[17];
  const float* proj_b = (const float*)d_in[18];
  const float* fc1_w = (const float*)d_in[19];
  const float* fc1_b = (const float*)d_in[20];
  const float* dw_w = (const float*)d_in[21];
  const float* dw_b = (const float*)d_in[22];
  const float* fc2_w = (const float*)d_in[23];
  const float* fc2_b = (const float*)d_in[24];

  // Workspace: 101,353,472 B = 96.7 MB (< 104 MB known-good).
  char* base = (char*)d_ws;
  bf16_t* xtb = (bf16_t*)(base);
  bf16_t* by1 = (bf16_t*)(base);
  bf16_t* bh1 = (bf16_t*)(base + 33554432);
  float* qb = (float*)(base + 33554432);
  float* outb = (float*)(base + 33554432);
  bf16_t* y2 = (bf16_t*)(base + 50331648);      // 33.5 MB [dwconv..fc2]
  float* partial = (float*)(base + 50331648);   // 13.1 MB [center..sim_cin]
  bf16_t* czt = (bf16_t*)(base + 67108864);
  bf16_t* obz = (bf16_t*)(base + 67108864);
  bf16_t* outb_b = (bf16_t*)(base + 67108864);
  bf16_t* wtb = (bf16_t*)(base + 80216064);
  bf16_t* wbz = (bf16_t*)(base + 96993280);
  float* cin = (float*)(base + 100124672);
  float* kb = (float*)(base + 100534272);
  float* vb = (float*)(base + 100943872);
  float* dout = (float*)d_out;

  bf16_t* conv2_wb = wbz;            // 65536
  bf16_t* conv3_wb = wbz + 65536;    // 25600
  bf16_t* q_wb = wbz + 91136;        // 65536
  bf16_t* proj_wb = wbz + 156672;    // 65536
  bf16_t* fc1_wb = wbz + 222208;     // 262144
  bf16_t* fc2_wb = wbz + 484352;     // 262144

  prologue<<<22436, 256, 0, stream>>>(x, mem, xtb, conv1_w, wtb, conv2_w, conv3_w,
                                      q_w, proj_w, fc1_w, fc2_w, wbz);
  conv1_mfma<<<256, 1024, 0, stream>>>(xtb, wtb, conv1_b, bh1);
  conv23<<<512, 512, 0, stream>>>(bh1, conv2_wb, conv2_b, conv3_wb, czt);
  softmax_rows<<<1600, 256, 0, stream>>>(czt);
  center_mfma<<<dim3(2, 16, 8), 256, 0, stream>>>(czt, xtb, partial);
  sim_cin<<<400, 256, 0, stream>>>(partial, sim_a, sim_b, ln_w, ln_b, cin);
  gemm_mfma<0, 1, 0, 0><<<dim3(2, 32, 4), 256, 0, stream>>>(
      xtb + (size_t)3 * NN * CC, q_wb, q_b, qb, 4096, 256, 256, 256,
      (size_t)4 * NN * CC, (size_t)NN * CC);
  gemm_kv<<<dim3(4, 7, 2), 256, 0, stream>>>(cin, k_w, k_b, v_w, v_b, kb, vb);
  attn2<<<dim3(512, 4), 256, 0, stream>>>(qb, kb, vb, obz);
  // proj + LN(+residual x) fused: writes outb (f32) + outb_b (bf16)
  gemm_ln<1><<<dim3(256, 1), 512, 0, stream>>>(obz, proj_wb, proj_b, ln_w, ln_b,
                                               x, outb, outb_b, 256, 0, 0);
  gemm_mfma<0, 1, 0, 1><<<dim3(8, 128, 1), 256, 0, stream>>>(outb_b, fc1_wb, fc1_b, by1,
                                                             16384, 1024, 256, 1024, 0, 0);
  dwconv_kernel<<<1024, 256, 0, stream>>>(by1, dw_w, dw_b, y2);
  // fc2 + LN(+residual outb) fused: writes dout directly
  gemm_ln<0><<<dim3(64, 4), 512, 0, stream>>>(y2, fc2_wb, fc2_b, ln_w, ln_b,
                                              outb, dout, nullptr, 1024,
                                              (size_t)NN * C4, (size_t)NN * CC);
}

// Round 13
// 767.435 us; speedup vs baseline: 1.1266x; 1.1266x over previous
//
#include <hip/hip_runtime.h>
#include <math.h>

#define NN 4096
#define CC 256
#define HH 64
#define BT 16
#define KCC 100
#define NHH 8
#define HDD 32
#define C4 1024

typedef unsigned short bf16_t;
typedef short s16x8 __attribute__((ext_vector_type(8)));
typedef float f32x4 __attribute__((ext_vector_type(4)));
typedef float f32x16 __attribute__((ext_vector_type(16)));

__device__ __forceinline__ float bf2f(bf16_t h) {
  return __uint_as_float(((unsigned)h) << 16);
}
__device__ __forceinline__ bf16_t f2bf(float f) {
  unsigned u = __float_as_uint(f);
  return (bf16_t)((u + 0x7FFFu + ((u >> 16) & 1u)) >> 16);
}

__device__ __forceinline__ float gelu_f(float x) {
  return 0.5f * x * (1.0f + erff(x * 0.7071067811865475f));
}

// async global->LDS, 16 B per lane; lds dest = wave-uniform base + lane*16
__device__ __forceinline__ void g2l16(const void* g, void* l) {
  __builtin_amdgcn_global_load_lds((const __attribute__((address_space(1))) void*)g,
                                   (__attribute__((address_space(3))) void*)l, 16, 0, 0);
}

__device__ __forceinline__ float block_sum256(float v) {
  __shared__ float sh[4];
#pragma unroll
  for (int off = 32; off; off >>= 1) v += __shfl_xor(v, off, 64);
  __syncthreads();
  if ((threadIdx.x & 63) == 0) sh[threadIdx.x >> 6] = v;
  __syncthreads();
  return sh[0] + sh[1] + sh[2] + sh[3];
}

__device__ __forceinline__ const float* xt_base(const float* x, const float* mem, int bt) {
  int b = bt >> 2, tt = bt & 3;
  return (tt < 3) ? (mem + (size_t)(b * 3 + tt) * NN * CC)
                  : (x + (size_t)b * NN * CC);
}

// fused prologue: [0,16384) build xtb; [16384,19520) transpose conv1_w -> wtb;
// [19520,22436) convert 6 weight mats to bf16 pack wbz.
__global__ __launch_bounds__(256) void prologue(const float* __restrict__ x,
                                                const float* __restrict__ mem,
                                                bf16_t* __restrict__ xtb,
                                                const float* __restrict__ w1,
                                                bf16_t* __restrict__ wtb,
                                                const float* __restrict__ c2w,
                                                const float* __restrict__ c3w,
                                                const float* __restrict__ qw,
                                                const float* __restrict__ pw,
                                                const float* __restrict__ f1w,
                                                const float* __restrict__ f2w,
                                                bf16_t* __restrict__ wbz) {
  int bid = blockIdx.x;
  int tid = threadIdx.x;
  if (bid < 16384) {
    int i = bid * 256 + tid;
    int c4 = i & 63;
    int n = (i >> 6) & 4095;
    int bt = i >> 18;
    const float* src = xt_base(x, mem, bt) + (size_t)n * CC + c4 * 4;
    float4 v = *(const float4*)src;
    ushort4 o;
    o.x = f2bf(v.x); o.y = f2bf(v.y); o.z = f2bf(v.z); o.w = f2bf(v.w);
    *(ushort4*)(xtb + (size_t)i * 4) = o;
  } else if (bid < 19520) {
    int i = (bid - 16384) * 256 + tid;  // < 802816 exactly
    int cj = i & 7;
    int t = i >> 3;
    int co = t & 63; t >>= 6;
    int oc = t & 3; t >>= 2;
    int kx = t % 7; t /= 7;
    int cq = t & 3; t >>= 2;
    int cg = t & 7;
    int ky = t >> 3;
    int ci = cg * 32 + oc * 8 + cj;
    int cog = cq * 64 + co;
    wtb[i] = f2bf(w1[((size_t)(cog * CC + ci) * 7 + ky) * 7 + kx]);
  } else {
    int j = (bid - 19520) * 256 + tid;  // < 746496 exactly
    float v;
    if (j < 65536) v = c2w[j];
    else if (j < 91136) v = c3w[j - 65536];
    else if (j < 156672) v = qw[j - 91136];
    else if (j < 222208) v = pw[j - 156672];
    else if (j < 484352) v = f1w[j - 222208];
    else v = f2w[j - 484352];
    wbz[j] = f2bf(v);
  }
}

// conv1 v9: best-known. 1024-thr (16-wave) block, 1/CU, 4 waves/SIMD via
// __launch_bounds__(1024,4). 32x32 MFMA, wave = 1 row x 64 px x 64 co
// (AI 32). Measured ~310us, MfmaUtil 63, occupancy ~45%. Plateau at AI 32.
__global__ __launch_bounds__(1024, 4) void conv1_mfma(const bf16_t* __restrict__ xtb,
                                                      const bf16_t* __restrict__ wtb,
                                                      const float* __restrict__ bias,
                                                      bf16_t* __restrict__ h1) {
  int bid = blockIdx.x;
  int cq = bid & 3;            // W-slice phase, XCD-aligned
  int rem = bid >> 2;          // 0..63
  int bt = rem & 15;
  int rb = rem >> 4;           // 0..3 : 16-row band
  int r0 = rb * 16;
  int co0 = cq * 64;
  int tid = threadIdx.x;
  int wv = tid >> 6;           // 0..15
  int lane = tid & 63;
  int l31 = lane & 31;
  int h = lane >> 5;           // 0..1 : k-half
  __shared__ __align__(16) short As[22][4][70][8];    // 98,560 B
  __shared__ __align__(16) short Ws[2][7][4][64][8];  // 57,344 B
  {
    s16x8 z = {0, 0, 0, 0, 0, 0, 0, 0};
    for (int i = tid; i < 22 * 4 * 70; i += 1024) *(s16x8*)((short*)As + i * 8) = z;
  }
  __syncthreads();
  f32x16 acc[2][2] = {};       // [mt][nt] 32x32 tiles
  const bf16_t* xb = xtb + (size_t)bt * (NN * CC);
  for (int cig = 0; cig < 8; ++cig) {
    int ci0 = cig * 32;
    // stage As: 22 rows x 4 ci-subgroups (halo rows outside image stay zero)
    for (int t = wv; t < 88; t += 16) {
      int rr = t >> 2, go = t & 3;
      int r = r0 - 3 + rr;
      if (r >= 0 && r < HH) {
        const bf16_t* gsrc = xb + ((size_t)(r * 64 + lane)) * CC + ci0 + go * 8;
        g2l16(gsrc, &As[rr][go][3][0]);
      }
    }
    // stage Ws buf0, ky=0
    {
      const bf16_t* wk = wtb + ((size_t)((0 * 8 + cig) * 4 + cq)) * (1792 * 8);
      for (int t = wv; t < 28; t += 16)
        g2l16(wk + (size_t)t * 512 + lane * 8, (short*)Ws[0] + t * 512);
    }
    __syncthreads();
    for (int ky = 0; ky < 7; ++ky) {
      int cur = ky & 1;
      if (ky < 6) {  // prefetch next ky's W taps into the other buffer
        const bf16_t* wk = wtb + ((size_t)(((ky + 1) * 8 + cig) * 4 + cq)) * (1792 * 8);
        for (int t = wv; t < 28; t += 16)
          g2l16(wk + (size_t)t * 512 + lane * 8, (short*)Ws[cur ^ 1] + t * 512);
      }
#pragma unroll
      for (int kx = 0; kx < 7; ++kx) {
        s16x8 fa[2][2], fb[2][2];  // [mt|nt][ks]
#pragma unroll
        for (int mt = 0; mt < 2; ++mt)
#pragma unroll
          for (int ks = 0; ks < 2; ++ks) {
            fa[mt][ks] = *(const s16x8*)&As[wv + ky][ks * 2 + h][mt * 32 + l31 + kx][0];
            fb[mt][ks] = *(const s16x8*)&Ws[cur][kx][ks * 2 + h][mt * 32 + l31][0];
          }
#pragma unroll
        for (int ks = 0; ks < 2; ++ks)
#pragma unroll
          for (int mt = 0; mt < 2; ++mt)
#pragma unroll
            for (int nt = 0; nt < 2; ++nt)
              acc[mt][nt] = __builtin_amdgcn_mfma_f32_32x32x16_bf16(
                  fa[mt][ks], fb[nt][ks], acc[mt][nt], 0, 0, 0);
      }
      __syncthreads();  // drains vmcnt: next Ws buffer ready; readers done
    }
  }
  int row = r0 + wv;
  const size_t xbase = (size_t)bt * (NN * CC);
#pragma unroll
  for (int nt = 0; nt < 2; ++nt) {
    int co = co0 + nt * 32 + l31;
    float bs = bias[co];
#pragma unroll
    for (int mt = 0; mt < 2; ++mt) {
#pragma unroll
      for (int rg = 0; rg < 16; ++rg) {
        int px = mt * 32 + (rg & 3) + 8 * (rg >> 2) + 4 * h;
        float vv = acc[mt][nt][rg] + bs;
        h1[xbase + (size_t)(row * 64 + px) * CC + co] = f2bf(gelu_f(vv));
      }
    }
  }
}

// conv23 v13: fused conv2(gelu) -> conv3 (unchanged).
__global__ __launch_bounds__(512) void conv23(const bf16_t* __restrict__ bh1,
                                              const bf16_t* __restrict__ w2,
                                              const float* __restrict__ b2,
                                              const bf16_t* __restrict__ w3,
                                              bf16_t* __restrict__ czt) {
  __shared__ __align__(16) char smem[126720];
  short (*As2)[72] = (short(*)[72])smem;
  short (*Bs2)[72] = (short(*)[72])(smem + 18432);
  short (*h2s)[264] = (short(*)[264])smem;
  short (*w3s)[264] = (short(*)[264])(smem + 67584);
  short (*ot)[132] = (short(*)[132])smem;
  int tid = threadIdx.x;
  int m0 = blockIdx.x * 128;
  int lane = tid & 63, wv = tid >> 6;
  int wm = wv & 1, wn = wv >> 1;
  int lm = lane & 15, g = lane >> 4;
  f32x4 acc[4][4] = {};
  int r1 = tid >> 2, kq = tid & 3;
  int br = tid >> 1, bq = (tid & 1) * 32;
  for (int k0 = 0; k0 < 256; k0 += 64) {
    *(s16x8*)&As2[r1][kq * 8] =
        *(const s16x8*)(bh1 + (size_t)(m0 + r1) * 256 + k0 + kq * 8);
    *(s16x8*)&As2[r1][32 + kq * 8] =
        *(const s16x8*)(bh1 + (size_t)(m0 + r1) * 256 + k0 + 32 + kq * 8);
#pragma unroll
    for (int j = 0; j < 4; ++j)
      *(s16x8*)&Bs2[br][bq + j * 8] =
          *(const s16x8*)(w2 + (size_t)br * 256 + k0 + bq + j * 8);
    __syncthreads();
#pragma unroll
    for (int ks = 0; ks < 2; ++ks) {
      s16x8 af[4], bf[4];
#pragma unroll
      for (int mt = 0; mt < 4; ++mt)
        af[mt] = *(const s16x8*)&As2[wm * 64 + mt * 16 + lm][ks * 32 + g * 8];
#pragma unroll
      for (int nt = 0; nt < 4; ++nt)
        bf[nt] = *(const s16x8*)&Bs2[wn * 64 + nt * 16 + lm][ks * 32 + g * 8];
#pragma unroll
      for (int mt = 0; mt < 4; ++mt)
#pragma unroll
        for (int nt = 0; nt < 4; ++nt)
          acc[mt][nt] = __builtin_amdgcn_mfma_f32_16x16x32_bf16(af[mt], bf[nt],
                                                                acc[mt][nt], 0, 0, 0);
    }
    __syncthreads();
  }
#pragma unroll
  for (int nt = 0; nt < 4; ++nt) {
    int c = wn * 64 + nt * 16 + lm;
    float bs = b2[c];
#pragma unroll
    for (int mt = 0; mt < 4; ++mt) {
#pragma unroll
      for (int rg = 0; rg < 4; ++rg) {
        int m = wm * 64 + mt * 16 + g * 4 + rg;
        h2s[m][c] = (short)f2bf(gelu_f(acc[mt][nt][rg] + bs));
      }
    }
  }
  {
    s16x8 z = {0, 0, 0, 0, 0, 0, 0, 0};
    for (int t = tid; t < 112 * 32; t += 512) {
      int rr = t >> 5, cc = (t & 31) * 8;
      s16x8 vv = z;
      if (rr < 100) vv = *(const s16x8*)(w3 + (size_t)rr * 256 + cc);
      *(s16x8*)&w3s[rr][cc] = vv;
    }
  }
  __syncthreads();
  f32x4 acc3[4][2] = {};
  int n_base = wn * 32;
#pragma unroll
  for (int k0 = 0; k0 < 256; k0 += 32) {
    s16x8 af[4], bf[2];
#pragma unroll
    for (int mt = 0; mt < 4; ++mt)
      af[mt] = *(const s16x8*)&h2s[wm * 64 + mt * 16 + lm][k0 + g * 8];
#pragma unroll
    for (int nt = 0; nt < 2; ++nt)
      bf[nt] = *(const s16x8*)&w3s[n_base + nt * 16 + lm][k0 + g * 8];
#pragma unroll
    for (int mt = 0; mt < 4; ++mt)
#pragma unroll
      for (int nt = 0; nt < 2; ++nt)
        acc3[mt][nt] = __builtin_amdgcn_mfma_f32_16x16x32_bf16(af[mt], bf[nt],
                                                               acc3[mt][nt], 0, 0, 0);
  }
  __syncthreads();
#pragma unroll
  for (int nt = 0; nt < 2; ++nt) {
    int kc = n_base + nt * 16 + lm;
    if (kc < 100) {
#pragma unroll
      for (int mt = 0; mt < 4; ++mt) {
#pragma unroll
        for (int rg = 0; rg < 4; ++rg) {
          int px = wm * 64 + mt * 16 + g * 4 + rg;
          ot[kc][px] = (short)f2bf(acc3[mt][nt][rg]);
        }
      }
    }
  }
  __syncthreads();
  for (int t = tid; t < 100 * 128; t += 512) {
    int kc = t >> 7, px = t & 127;
    czt[(size_t)kc * 65536 + m0 + px] = (bf16_t)ot[kc][px];
  }
}

// bf16 MFMA GEMM, K-step 64 (v12)
template <int GELU, int BIAS, int TOUT, int OBF>
__global__ __launch_bounds__(256) void gemm_mfma(const bf16_t* __restrict__ A,
                                                 const bf16_t* __restrict__ W,
                                                 const float* __restrict__ bias,
                                                 void* __restrict__ outp,
                                                 int M, int N, int K, int ldo,
                                                 size_t aStr, size_t oStr) {
  __shared__ short As[128][72];
  __shared__ short Bs[128][72];
  A += (size_t)blockIdx.z * aStr;
  size_t obase = (size_t)blockIdx.z * oStr;
  int tid = threadIdx.x;
  int n0 = blockIdx.x * 128, m0 = blockIdx.y * 128;
  int lane = tid & 63, wv = tid >> 6;
  int wm = wv & 1, wn = wv >> 1;
  int lm = lane & 15, g = lane >> 4;
  f32x4 acc[4][4] = {};
  int r1 = tid >> 2, kq = tid & 3;
  int r2 = r1 + 64;
  for (int k0 = 0; k0 < K; k0 += 64) {
    *(s16x8*)&As[r1][kq * 8] = *(const s16x8*)(A + (size_t)(m0 + r1) * K + k0 + kq * 8);
    *(s16x8*)&As[r1][32 + kq * 8] =
        *(const s16x8*)(A + (size_t)(m0 + r1) * K + k0 + 32 + kq * 8);
    *(s16x8*)&As[r2][kq * 8] = *(const s16x8*)(A + (size_t)(m0 + r2) * K + k0 + kq * 8);
    *(s16x8*)&As[r2][32 + kq * 8] =
        *(const s16x8*)(A + (size_t)(m0 + r2) * K + k0 + 32 + kq * 8);
    s16x8 z = {0, 0, 0, 0, 0, 0, 0, 0};
    s16x8 b1 = z, b2 = z, b3 = z, b4 = z;
    if (n0 + r1 < N) {
      b1 = *(const s16x8*)(W + (size_t)(n0 + r1) * K + k0 + kq * 8);
      b2 = *(const s16x8*)(W + (size_t)(n0 + r1) * K + k0 + 32 + kq * 8);
    }
    if (n0 + r2 < N) {
      b3 = *(const s16x8*)(W + (size_t)(n0 + r2) * K + k0 + kq * 8);
      b4 = *(const s16x8*)(W + (size_t)(n0 + r2) * K + k0 + 32 + kq * 8);
    }
    *(s16x8*)&Bs[r1][kq * 8] = b1;
    *(s16x8*)&Bs[r1][32 + kq * 8] = b2;
    *(s16x8*)&Bs[r2][kq * 8] = b3;
    *(s16x8*)&Bs[r2][32 + kq * 8] = b4;
    __syncthreads();
#pragma unroll
    for (int ks = 0; ks < 2; ++ks) {
      s16x8 af[4], bf[4];
#pragma unroll
      for (int mt = 0; mt < 4; ++mt)
        af[mt] = *(const s16x8*)&As[wm * 64 + mt * 16 + lm][ks * 32 + g * 8];
#pragma unroll
      for (int nt = 0; nt < 4; ++nt)
        bf[nt] = *(const s16x8*)&Bs[wn * 64 + nt * 16 + lm][ks * 32 + g * 8];
#pragma unroll
      for (int mt = 0; mt < 4; ++mt)
#pragma unroll
        for (int nt = 0; nt < 4; ++nt)
          acc[mt][nt] = __builtin_amdgcn_mfma_f32_16x16x32_bf16(af[mt], bf[nt],
                                                                acc[mt][nt], 0, 0, 0);
    }
    __syncthreads();
  }
#pragma unroll
  for (int nt = 0; nt < 4; ++nt) {
    int n = n0 + wn * 64 + nt * 16 + lm;
    if (n >= N) continue;
    float bs = BIAS ? bias[n] : 0.f;
#pragma unroll
    for (int mt = 0; mt < 4; ++mt) {
#pragma unroll
      for (int rg = 0; rg < 4; ++rg) {
        int m = m0 + wm * 64 + mt * 16 + g * 4 + rg;
        float v = acc[mt][nt][rg] + bs;
        if (GELU) v = gelu_f(v);
        size_t idx = obase + (TOUT ? ((size_t)n * ldo + m) : ((size_t)m * ldo + n));
        if (OBF)
          ((bf16_t*)outp)[idx] = f2bf(v);
        else
          ((float*)outp)[idx] = v;
      }
    }
  }
}

// gemm_ln v14: 128x256-tile GEMM (full N=256 rows in-block) + per-row
// LayerNorm + residual epilogue. 512 thr / 8 waves (wm rows, wn cols),
// BK=64. Epilogue: 2 phases of 64 rows staged f32 into the dead As/Bs
// arena (Ls[64][260]); wave-per-row shfl reduction == add_ln v12 order.
// A/dst_b alias (obz==outb_b) safe: block reads only rows [m0,m0+128)
// before the epilogue and writes exactly those rows.
template <int WB>
__global__ __launch_bounds__(512) void gemm_ln(const bf16_t* __restrict__ A,
                                               const bf16_t* __restrict__ W,
                                               const float* __restrict__ bias,
                                               const float* __restrict__ lnw,
                                               const float* __restrict__ lnb,
                                               const float* __restrict__ res,
                                               float* __restrict__ dst,
                                               bf16_t* __restrict__ dst_b,
                                               int K, size_t aStr, size_t oStr) {
  __shared__ __align__(16) char smem[66560];
  short (*As)[72] = (short(*)[72])smem;            // 18,432 B
  short (*Bs)[72] = (short(*)[72])(smem + 18432);  // 36,864 B
  float (*Ls)[260] = (float(*)[260])smem;          // 66,560 B (epilogue)
  int tid = threadIdx.x;
  int m0 = blockIdx.x * 128;
  A += (size_t)blockIdx.y * aStr;
  size_t obase = (size_t)blockIdx.y * oStr;
  int lane = tid & 63, wv = tid >> 6;
  int wm = wv & 1, wn = wv >> 1;
  int lm = lane & 15, g = lane >> 4;
  f32x4 acc[4][4] = {};
  int r1 = tid >> 2, kq = tid & 3;
  int br = tid >> 1, bq = (tid & 1) * 32;
  for (int k0 = 0; k0 < K; k0 += 64) {
    *(s16x8*)&As[r1][kq * 8] = *(const s16x8*)(A + (size_t)(m0 + r1) * K + k0 + kq * 8);
    *(s16x8*)&As[r1][32 + kq * 8] =
        *(const s16x8*)(A + (size_t)(m0 + r1) * K + k0 + 32 + kq * 8);
#pragma unroll
    for (int j = 0; j < 4; ++j)
      *(s16x8*)&Bs[br][bq + j * 8] =
          *(const s16x8*)(W + (size_t)br * K + k0 + bq + j * 8);
    __syncthreads();
#pragma unroll
    for (int ks = 0; ks < 2; ++ks) {
      s16x8 af[4], bf[4];
#pragma unroll
      for (int mt = 0; mt < 4; ++mt)
        af[mt] = *(const s16x8*)&As[wm * 64 + mt * 16 + lm][ks * 32 + g * 8];
#pragma unroll
      for (int nt = 0; nt < 4; ++nt)
        bf[nt] = *(const s16x8*)&Bs[wn * 64 + nt * 16 + lm][ks * 32 + g * 8];
#pragma unroll
      for (int mt = 0; mt < 4; ++mt)
#pragma unroll
        for (int nt = 0; nt < 4; ++nt)
          acc[mt][nt] = __builtin_amdgcn_mfma_f32_16x16x32_bf16(af[mt], bf[nt],
                                                                acc[mt][nt], 0, 0, 0);
    }
    __syncthreads();
  }
  // 2-phase LN epilogue over the 128 rows (full N in-block).
#pragma unroll
  for (int ph = 0; ph < 2; ++ph) {
    if (ph) __syncthreads();  // previous phase's Ls reads done
    if (wm == ph) {
#pragma unroll
      for (int nt = 0; nt < 4; ++nt) {
        int c = wn * 64 + nt * 16 + lm;
        float bs = bias[c];
#pragma unroll
        for (int mt = 0; mt < 4; ++mt) {
#pragma unroll
          for (int rg = 0; rg < 4; ++rg) {
            int m = mt * 16 + g * 4 + rg;
            Ls[m][c] = acc[mt][nt][rg] + bs;  // (16g+lm)%32 -> 2-way, free
          }
        }
      }
    }
    __syncthreads();
#pragma unroll
    for (int i = 0; i < 8; ++i) {
      int mr = wv * 8 + i;
      size_t grow = (size_t)(m0 + ph * 64 + mr);
      int c = lane * 4;
      float4 v = *(const float4*)&Ls[mr][c];
      float s = v.x + v.y + v.z + v.w;
#pragma unroll
      for (int off = 32; off; off >>= 1) s += __shfl_xor(s, off, 64);
      float mmean = s * (1.f / CC);
      float d0 = v.x - mmean, d1 = v.y - mmean, d2 = v.z - mmean, d3 = v.w - mmean;
      float q = d0 * d0 + d1 * d1 + d2 * d2 + d3 * d3;
#pragma unroll
      for (int off = 32; off; off >>= 1) q += __shfl_xor(q, off, 64);
      float inv = rsqrtf(q * (1.f / CC) + 1e-5f);
      float4 r4 = *(const float4*)&res[obase + grow * CC + c];
      float4 lw = *(const float4*)&lnw[c];
      float4 lb = *(const float4*)&lnb[c];
      float4 o;
      o.x = r4.x + d0 * inv * lw.x + lb.x;
      o.y = r4.y + d1 * inv * lw.y + lb.y;
      o.z = r4.z + d2 * inv * lw.z + lb.z;
      o.w = r4.w + d3 * inv * lw.w + lb.w;
      *(float4*)&dst[obase + grow * CC + c] = o;
      if (WB) {
        ushort4 ob;
        ob.x = f2bf(o.x); ob.y = f2bf(o.y); ob.z = f2bf(o.z); ob.w = f2bf(o.w);
        *(ushort4*)&dst_b[obase + grow * CC + c] = ob;
      }
    }
  }
}

// fused k/v projections: z=0 -> k, z=1 -> v. M=400, N=256, K=256.
__global__ __launch_bounds__(256) void gemm_kv(const float* __restrict__ cin,
                                               const float* __restrict__ kw,
                                               const float* __restrict__ kbias,
                                               const float* __restrict__ vw,
                                               const float* __restrict__ vbias,
                                               float* __restrict__ kout,
                                               float* __restrict__ vout) {
  const float* Wm = blockIdx.z ? vw : kw;
  const float* bias = blockIdx.z ? vbias : kbias;
  float* outp = blockIdx.z ? vout : kout;
  const int M = 400, N = 256, K = 256;
  __shared__ float As[16][68];
  __shared__ float Ws[16][68];
  int tid = threadIdx.x;
  int n0 = blockIdx.x * 64, m0 = blockIdx.y * 64;
  int txn = tid & 15, tym = tid >> 4;
  int mi = tid >> 2, kq = (tid & 3) * 4;
  float acc[4][4] = {};
  for (int k0 = 0; k0 < K; k0 += 16) {
    float4 av = {0, 0, 0, 0}, wvv = {0, 0, 0, 0};
    if (m0 + mi < M) av = *(const float4*)&cin[(size_t)(m0 + mi) * K + k0 + kq];
    if (n0 + mi < N) wvv = *(const float4*)&Wm[(size_t)(n0 + mi) * K + k0 + kq];
    As[kq + 0][mi] = av.x; As[kq + 1][mi] = av.y; As[kq + 2][mi] = av.z; As[kq + 3][mi] = av.w;
    Ws[kq + 0][mi] = wvv.x; Ws[kq + 1][mi] = wvv.y; Ws[kq + 2][mi] = wvv.z; Ws[kq + 3][mi] = wvv.w;
    __syncthreads();
#pragma unroll
    for (int ki = 0; ki < 16; ++ki) {
      float4 a4 = *(const float4*)&As[ki][tym * 4];
      float4 w4 = *(const float4*)&Ws[ki][txn * 4];
      float am[4] = {a4.x, a4.y, a4.z, a4.w};
      float wn[4] = {w4.x, w4.y, w4.z, w4.w};
#pragma unroll
      for (int i = 0; i < 4; ++i)
#pragma unroll
        for (int j = 0; j < 4; ++j) acc[i][j] += am[i] * wn[j];
    }
    __syncthreads();
  }
#pragma unroll
  for (int i = 0; i < 4; ++i) {
    int m = m0 + tym * 4 + i;
    if (m >= M) continue;
#pragma unroll
    for (int j = 0; j < 4; ++j) {
      int n = n0 + txn * 4 + j;
      outp[(size_t)m * 256 + n] = acc[i][j] + bias[n];
    }
  }
}

// 1600 rows of 4096 bf16, softmax in place; thread owns 16 contiguous elems
__global__ __launch_bounds__(256) void softmax_rows(bf16_t* __restrict__ p) {
  __shared__ float sh[8];
  int tid = threadIdx.x;
  bf16_t* base = p + (size_t)blockIdx.x * NN + tid * 16;
  s16x8 a = *(const s16x8*)base;
  s16x8 b = *(const s16x8*)(base + 8);
  float vals[16];
#pragma unroll
  for (int j = 0; j < 8; ++j) {
    vals[j] = bf2f((bf16_t)a[j]);
    vals[8 + j] = bf2f((bf16_t)b[j]);
  }
  float mx = -1e30f;
#pragma unroll
  for (int j = 0; j < 16; ++j) mx = fmaxf(mx, vals[j]);
#pragma unroll
  for (int off = 32; off; off >>= 1) mx = fmaxf(mx, __shfl_xor(mx, off, 64));
  if ((tid & 63) == 0) sh[tid >> 6] = mx;
  __syncthreads();
  mx = fmaxf(fmaxf(sh[0], sh[1]), fmaxf(sh[2], sh[3]));
  float s = 0.f;
#pragma unroll
  for (int j = 0; j < 16; ++j) {
    vals[j] = expf(vals[j] - mx);
    s += vals[j];
  }
#pragma unroll
  for (int off = 32; off; off >>= 1) s += __shfl_xor(s, off, 64);
  if ((tid & 63) == 0) sh[4 + (tid >> 6)] = s;
  __syncthreads();
  s = sh[4] + sh[5] + sh[6] + sh[7];
  float inv = 1.f / s;
  s16x8 oa, ob;
#pragma unroll
  for (int j = 0; j < 8; ++j) {
    oa[j] = (short)f2bf(vals[j] * inv);
    ob[j] = (short)f2bf(vals[8 + j] * inv);
  }
  *(s16x8*)base = oa;
  *(s16x8*)(base + 8) = ob;
}

// center via MFMA split-K (8 chunks of 512): partial[nc][bt][kc][c].
__global__ __launch_bounds__(256) void center_mfma(const bf16_t* __restrict__ soft,
                                                   const bf16_t* __restrict__ xtb,
                                                   float* __restrict__ partial) {
  int c0 = blockIdx.x * 128;
  int bt = blockIdx.y;
  int nc = blockIdx.z;
  int tid = threadIdx.x;
  int lane = tid & 63, wv = tid >> 6;
  int wm = wv & 1, wn = wv >> 1;
  int lm = lane & 15, g = lane >> 4;
  __shared__ short As[128][40];
  __shared__ short Bs[128][40];
  f32x4 acc[4][4] = {};
  int r1 = tid >> 2, kq = tid & 3;
  int r2 = r1 + 64;
  int bk = tid & 31, bc = (tid >> 5) * 16;
  const bf16_t* sb = soft + (size_t)bt * NN + (size_t)nc * 512;
  const bf16_t* xb = xtb + ((size_t)bt * NN + (size_t)nc * 512) * CC + c0;
  for (int k0 = 0; k0 < 512; k0 += 32) {
    *(s16x8*)&As[r1][kq * 8] =
        *(const s16x8*)(sb + (size_t)r1 * (BT * NN) + k0 + kq * 8);
    if (r2 < KCC)
      *(s16x8*)&As[r2][kq * 8] =
          *(const s16x8*)(sb + (size_t)r2 * (BT * NN) + k0 + kq * 8);
    s16x8 v0 = *(const s16x8*)(xb + (size_t)(k0 + bk) * CC + bc);
    s16x8 v1 = *(const s16x8*)(xb + (size_t)(k0 + bk) * CC + bc + 8);
#pragma unroll
    for (int j = 0; j < 8; ++j) Bs[bc + j][bk] = v0[j];
#pragma unroll
    for (int j = 0; j < 8; ++j) Bs[bc + 8 + j][bk] = v1[j];
    __syncthreads();
    s16x8 af[4], bf[4];
#pragma unroll
    for (int mt = 0; mt < 4; ++mt)
      af[mt] = *(const s16x8*)&As[wm * 64 + mt * 16 + lm][g * 8];
#pragma unroll
    for (int nt = 0; nt < 4; ++nt)
      bf[nt] = *(const s16x8*)&Bs[wn * 64 + nt * 16 + lm][g * 8];
#pragma unroll
    for (int mt = 0; mt < 4; ++mt)
#pragma unroll
      for (int nt = 0; nt < 4; ++nt)
        acc[mt][nt] = __builtin_amdgcn_mfma_f32_16x16x32_bf16(af[mt], bf[nt],
                                                              acc[mt][nt], 0, 0, 0);
    __syncthreads();
  }
  size_t obase = ((size_t)nc * BT + bt) * (KCC * CC);
#pragma unroll
  for (int nt = 0; nt < 4; ++nt) {
    int c = c0 + wn * 64 + nt * 16 + lm;
#pragma unroll
    for (int mt = 0; mt < 4; ++mt) {
#pragma unroll
      for (int rg = 0; rg < 4; ++rg) {
        int m = wm * 64 + mt * 16 + g * 4 + rg;
        if (m < KCC) partial[obase + (size_t)m * CC + c] = acc[mt][nt][rg];
      }
    }
  }
}

// cosine-sim gating + LN -> cin[b][kc][c]. v13 batched reductions.
__global__ __launch_bounds__(256) void sim_cin(const float* __restrict__ partial,
                                               const float* __restrict__ alpha_p,
                                               const float* __restrict__ beta_p,
                                               const float* __restrict__ lnw,
                                               const float* __restrict__ lnb,
                                               float* __restrict__ cin) {
  int b = blockIdx.x / KCC, kc = blockIdx.x % KCC;
  int c = threadIdx.x;
  float p0 = 0.f, p1 = 0.f, p2 = 0.f, lst = 0.f;
#pragma unroll
  for (int nc = 0; nc < 8; ++nc) {
    size_t base = ((size_t)nc * BT) * KCC * CC;
    p0 += partial[base + ((size_t)(b * 4 + 0) * KCC + kc) * CC + c];
    p1 += partial[base + ((size_t)(b * 4 + 1) * KCC + kc) * CC + c];
    p2 += partial[base + ((size_t)(b * 4 + 2) * KCC + kc) * CC + c];
    lst += partial[base + ((size_t)(b * 4 + 3) * KCC + kc) * CC + c];
  }
  float v7[7] = {lst * lst, p0 * p0, p1 * p1, p2 * p2,
                 lst * p0, lst * p1, lst * p2};
#pragma unroll
  for (int off = 32; off; off >>= 1)
#pragma unroll
    for (int j = 0; j < 7; ++j) v7[j] += __shfl_xor(v7[j], off, 64);
  __shared__ float sh7[4][8];
  if ((threadIdx.x & 63) == 0)
#pragma unroll
    for (int j = 0; j < 7; ++j) sh7[threadIdx.x >> 6][j] = v7[j];
  __syncthreads();
  float s7[7];
#pragma unroll
  for (int j = 0; j < 7; ++j)
    s7[j] = sh7[0][j] + sh7[1][j] + sh7[2][j] + sh7[3][j];
  float ll = s7[0], q0 = s7[1], q1 = s7[2], q2 = s7[3];
  float d0 = s7[4], d1 = s7[5], d2 = s7[6];
  float alpha = alpha_p[0], beta = beta_p[0];
  float nl = sqrtf(ll);
  float c0 = 1.f / (1.f + expf(-(beta + alpha * (d0 / fmaxf(nl * sqrtf(q0), 1e-8f)))));
  float c1 = 1.f / (1.f + expf(-(beta + alpha * (d1 / fmaxf(nl * sqrtf(q1), 1e-8f)))));
  float c2 = 1.f / (1.f + expf(-(beta + alpha * (d2 / fmaxf(nl * sqrtf(q2), 1e-8f)))));
  float v = lst + c0 * p0 + c1 * p1 + c2 * p2;
  float m = block_sum256(v) * (1.f / CC);
  float dv = v - m;
  float var = block_sum256(dv * dv) * (1.f / CC);
  cin[((size_t)b * KCC + kc) * CC + c] = dv * rsqrtf(var + 1e-5f) * lnw[c] + lnb[c];
}

// attention v2: block = (8 query rows, b). K tiled through LDS, V read once.
__global__ __launch_bounds__(256) void attn2(const float* __restrict__ q,
                                             const float* __restrict__ kb,
                                             const float* __restrict__ vb,
                                             bf16_t* __restrict__ ob) {
  int b = blockIdx.y;
  int n0 = blockIdx.x * 8;
  int tid = threadIdx.x;
  __shared__ float qs[8][256];
  __shared__ float Ks[32][257];
  __shared__ float sc[8][8][104];
#pragma unroll
  for (int r = 0; r < 8; ++r)
    qs[r][tid] = q[((size_t)b * NN + n0 + r) * CC + tid] * 0.17677669529663687f;
  int nn = tid >> 5, kcl = tid & 31;
  for (int kt = 0; kt < 4; ++kt) {
    int kbase = kt * 32;
    int rows = (kbase + 32 <= KCC) ? 32 : (KCC - kbase);
    __syncthreads();
    for (int idx = tid; idx < rows * 256; idx += 256) {
      int rr = idx >> 8, cc = idx & 255;
      Ks[rr][cc] = kb[((size_t)b * KCC + kbase + rr) * CC + cc];
    }
    __syncthreads();
    if (kcl < rows) {
#pragma unroll
      for (int h = 0; h < NHH; ++h) {
        float s = 0.f;
#pragma unroll
        for (int d = 0; d < HDD; ++d) s += qs[nn][h * HDD + d] * Ks[kcl][h * HDD + d];
        sc[nn][h][kbase + kcl] = s;
      }
    }
  }
  __syncthreads();
  {
    int tnn = tid >> 5, th = (tid >> 2) & 7, j = tid & 3;
    float mx = -1e30f;
    for (int kc = j * 25; kc < j * 25 + 25; ++kc) mx = fmaxf(mx, sc[tnn][th][kc]);
    mx = fmaxf(mx, __shfl_xor(mx, 1, 64));
    mx = fmaxf(mx, __shfl_xor(mx, 2, 64));
    float sm = 0.f;
    for (int kc = j * 25; kc < j * 25 + 25; ++kc) {
      float e = expf(sc[tnn][th][kc] - mx);
      sc[tnn][th][kc] = e;
      sm += e;
    }
    sm += __shfl_xor(sm, 1, 64);
    sm += __shfl_xor(sm, 2, 64);
    float inv = 1.f / sm;
    for (int kc = j * 25; kc < j * 25 + 25; ++kc) sc[tnn][th][kc] *= inv;
  }
  __syncthreads();
  float o[8] = {0, 0, 0, 0, 0, 0, 0, 0};
  int h = tid >> 5;
  for (int kc = 0; kc < KCC; ++kc) {
    float v = vb[((size_t)b * KCC + kc) * CC + tid];
#pragma unroll
    for (int r = 0; r < 8; ++r) o[r] += sc[r][h][kc] * v;
  }
#pragma unroll
  for (int r = 0; r < 8; ++r)
    ob[((size_t)b * NN + n0 + r) * CC + tid] = f2bf(o[r]);
}

// dwconv v14: sliding-window rows. block = 16-px row segment (grid 1024),
// 3-col register window rotated along w: ~3.4 loads/px vs 9.
__global__ __launch_bounds__(256) void dwconv_kernel(const bf16_t* __restrict__ y1,
                                                     const float* __restrict__ dww,
                                                     const float* __restrict__ dwb,
                                                     bf16_t* __restrict__ y2) {
  int t = blockIdx.x;          // b(4) x h(64) x quarter(4)
  int b = t >> 8;
  int h = (t >> 2) & 63;
  int qd = t & 3;
  int w0 = qd << 4;
  int c40 = threadIdx.x * 4;
  float wreg[4][9];
#pragma unroll
  for (int j = 0; j < 4; ++j)
#pragma unroll
    for (int k = 0; k < 9; ++k) wreg[j][k] = dww[(size_t)(c40 + j) * 9 + k];
  float b4[4];
#pragma unroll
  for (int j = 0; j < 4; ++j) b4[j] = dwb[c40 + j];
  const bf16_t* bb = y1 + (size_t)b * NN * C4 + c40;
  bf16_t* obp = y2 + (size_t)b * NN * C4 + c40;
  ushort4 z4; z4.x = 0; z4.y = 0; z4.z = 0; z4.w = 0;
  bool rok[3];
  size_t rbase[3];
#pragma unroll
  for (int dy = 0; dy < 3; ++dy) {
    int r = h - 1 + dy;
    rok[dy] = (r >= 0 && r < HH);
    rbase[dy] = (size_t)(rok[dy] ? r : 0) * 64 * C4;
  }
  ushort4 u0[3], u1[3], u2[3];
#pragma unroll
  for (int dy = 0; dy < 3; ++dy) {
    u0[dy] = (rok[dy] && w0 > 0) ? *(const ushort4*)(bb + rbase[dy] + (size_t)(w0 - 1) * C4) : z4;
    u1[dy] = rok[dy] ? *(const ushort4*)(bb + rbase[dy] + (size_t)w0 * C4) : z4;
  }
  for (int w = w0; w < w0 + 16; ++w) {
    bool cok = (w + 1 < 64);
#pragma unroll
    for (int dy = 0; dy < 3; ++dy)
      u2[dy] = (rok[dy] && cok) ? *(const ushort4*)(bb + rbase[dy] + (size_t)(w + 1) * C4) : z4;
    float acc0 = 0.f, acc1 = 0.f, acc2 = 0.f, acc3 = 0.f;
#pragma unroll
    for (int dy = 0; dy < 3; ++dy) {
      acc0 += bf2f(u0[dy].x) * wreg[0][dy * 3 + 0] + bf2f(u1[dy].x) * wreg[0][dy * 3 + 1] +
              bf2f(u2[dy].x) * wreg[0][dy * 3 + 2];
      acc1 += bf2f(u0[dy].y) * wreg[1][dy * 3 + 0] + bf2f(u1[dy].y) * wreg[1][dy * 3 + 1] +
              bf2f(u2[dy].y) * wreg[1][dy * 3 + 2];
      acc2 += bf2f(u0[dy].z) * wreg[2][dy * 3 + 0] + bf2f(u1[dy].z) * wreg[2][dy * 3 + 1] +
              bf2f(u2[dy].z) * wreg[2][dy * 3 + 2];
      acc3 += bf2f(u0[dy].w) * wreg[3][dy * 3 + 0] + bf2f(u1[dy].w) * wreg[3][dy * 3 + 1] +
              bf2f(u2[dy].w) * wreg[3][dy * 3 + 2];
    }
    ushort4 o;
    o.x = f2bf(gelu_f(acc0 + b4[0]));
    o.y = f2bf(gelu_f(acc1 + b4[1]));
    o.z = f2bf(gelu_f(acc2 + b4[2]));
    o.w = f2bf(gelu_f(acc3 + b4[3]));
    *(ushort4*)(obp + (size_t)(h * 64 + w) * C4) = o;
#pragma unroll
    for (int dy = 0; dy < 3; ++dy) {
      u0[dy] = u1[dy];
      u1[dy] = u2[dy];
    }
  }
}

extern "C" void kernel_launch(void* const* d_in, const int* in_sizes, int n_in,
                              void* d_out, int out_size, void* d_ws, size_t ws_size,
                              hipStream_t stream) {
  const float* x = (const float*)d_in[0];
  const float* mem = (const float*)d_in[1];
  const float* conv1_w = (const float*)d_in[2];
  const float* conv1_b = (const float*)d_in[3];
  const float* conv2_w = (const float*)d_in[4];
  const float* conv2_b = (const float*)d_in[5];
  const float* conv3_w = (const float*)d_in[6];
  const float* sim_a = (const float*)d_in[7];
  const float* sim_b = (const float*)d_in[8];
  const float* ln_w = (const float*)d_in[9];
  const float* ln_b = (const float*)d_in[10];
  const float* q_w = (const float*)d_in[11];
  const float* q_b = (const float*)d_in[12];
  const float* k_w = (const float*)d_in[13];
  const float* k_b = (const float*)d_in[14];
  const float* v_w = (const float*)d_in[15];
  const float* v_b = (const float*)d_in[16];
  const float* proj_w = (const float*)d_in[17];
  const float* proj_b = (const float*)d_in[18];
  const float* fc1_w = (const float*)d_in[19];
  const float* fc1_b = (const float*)d_in[20];
  const float* dw_w = (const float*)d_in[21];
  const float* dw_b = (const float*)d_in[22];
  const float* fc2_w = (const float*)d_in[23];
  const float* fc2_b = (const float*)d_in[24];

  // Workspace: 101,353,472 B = 96.7 MB (< 104 MB known-good).
  char* base = (char*)d_ws;
  bf16_t* xtb = (bf16_t*)(base);
  bf16_t* by1 = (bf16_t*)(base);
  bf16_t* bh1 = (bf16_t*)(base + 33554432);
  float* qb = (float*)(base + 33554432);
  float* outb = (float*)(base + 33554432);
  bf16_t* y2 = (bf16_t*)(base + 50331648);      // 33.5 MB [dwconv..fc2]
  float* partial = (float*)(base + 50331648);   // 13.1 MB [center..sim_cin]
  bf16_t* czt = (bf16_t*)(base + 67108864);
  bf16_t* obz = (bf16_t*)(base + 67108864);
  bf16_t* outb_b = (bf16_t*)(base + 67108864);
  bf16_t* wtb = (bf16_t*)(base + 80216064);
  bf16_t* wbz = (bf16_t*)(base + 96993280);
  float* cin = (float*)(base + 100124672);
  float* kb = (float*)(base + 100534272);
  float* vb = (float*)(base + 100943872);
  float* dout = (float*)d_out;

  bf16_t* conv2_wb = wbz;            // 65536
  bf16_t* conv3_wb = wbz + 65536;    // 25600
  bf16_t* q_wb = wbz + 91136;        // 65536
  bf16_t* proj_wb = wbz + 156672;    // 65536
  bf16_t* fc1_wb = wbz + 222208;     // 262144
  bf16_t* fc2_wb = wbz + 484352;     // 262144

  prologue<<<22436, 256, 0, stream>>>(x, mem, xtb, conv1_w, wtb, conv2_w, conv3_w,
                                      q_w, proj_w, fc1_w, fc2_w, wbz);
  conv1_mfma<<<256, 1024, 0, stream>>>(xtb, wtb, conv1_b, bh1);
  conv23<<<512, 512, 0, stream>>>(bh1, conv2_wb, conv2_b, conv3_wb, czt);
  softmax_rows<<<1600, 256, 0, stream>>>(czt);
  center_mfma<<<dim3(2, 16, 8), 256, 0, stream>>>(czt, xtb, partial);
  sim_cin<<<400, 256, 0, stream>>>(partial, sim_a, sim_b, ln_w, ln_b, cin);
  gemm_mfma<0, 1, 0, 0><<<dim3(2, 32, 4), 256, 0, stream>>>(
      xtb + (size_t)3 * NN * CC, q_wb, q_b, qb, 4096, 256, 256, 256,
      (size_t)4 * NN * CC, (size_t)NN * CC);
  gemm_kv<<<dim3(4, 7, 2), 256, 0, stream>>>(cin, k_w, k_b, v_w, v_b, kb, vb);
  attn2<<<dim3(512, 4), 256, 0, stream>>>(qb, kb, vb, obz);
  // proj + LN(+residual x) fused: writes outb (f32) + outb_b (bf16)
  gemm_ln<1><<<dim3(128, 1), 512, 0, stream>>>(obz, proj_wb, proj_b, ln_w, ln_b,
                                               x, outb, outb_b, 256, 0, 0);
  gemm_mfma<0, 1, 0, 1><<<dim3(8, 128, 1), 256, 0, stream>>>(outb_b, fc1_wb, fc1_b, by1,
                                                             16384, 1024, 256, 1024, 0, 0);
  dwconv_kernel<<<1024, 256, 0, stream>>>(by1, dw_w, dw_b, y2);
  // fc2 + LN(+residual outb) fused: writes dout directly
  gemm_ln<0><<<dim3(32, 4), 512, 0, stream>>>(y2, fc2_wb, fc2_b, ln_w, ln_b,
                                              outb, dout, nullptr, 1024,
                                              (size_t)NN * C4, (size_t)NN * CC);
}